// Round 5
// baseline (270.301 us; speedup 1.0000x reference)
//
#include <hip/hip_runtime.h>
#include <hip/hip_bf16.h>

typedef __attribute__((ext_vector_type(8))) short short8;
typedef __attribute__((ext_vector_type(4))) float float4v;

#define NB 32
#define LL 128
#define DDIM 300
#define DP 320
#define KDIM 50
#define TP 40    // Tt pitch in bf16 elems (80B)

__device__ __forceinline__ unsigned short f2bf(float x) {
    unsigned int u = __float_as_uint(x);
    unsigned int r = (u + 0x7FFFu + ((u >> 16) & 1u)) >> 16;
    return (unsigned short)r;
}
__device__ __forceinline__ unsigned int pack2bf(float a, float b) {
    return (unsigned int)f2bf(a) | ((unsigned int)f2bf(b) << 16);
}
__device__ __forceinline__ float4v mfma16(short8 a, short8 b, float4v c) {
    return __builtin_amdgcn_mfma_f32_16x16x32_bf16(a, b, c, 0, 0, 0);
}
// async global->LDS DMA, 16B per lane; LDS dest = uniform base + lane*16
__device__ __forceinline__ void dma16(const void* g, void* l) {
    __builtin_amdgcn_global_load_lds(
        (const __attribute__((address_space(1))) unsigned int*)g,
        (__attribute__((address_space(3))) unsigned int*)l, 16, 0, 0);
}

// ---------- prep: e1/e2 -> bf16, D padded 300->320 with zeros ----------
__global__ void prep_convert(const float* __restrict__ e1, const float* __restrict__ e2,
                             unsigned short* __restrict__ e1b, unsigned short* __restrict__ e2b) {
    int gid = blockIdx.x * 256 + threadIdx.x;     // 8192 rows * 40 granules
    int row = gid / 40;
    int d0 = (gid % 40) * 8;
    const float* src;
    unsigned short* dst;
    if (row < 4096) { src = e1 + (size_t)row * DDIM; dst = e1b + (size_t)row * DP + d0; }
    else { int r = row - 4096; src = e2 + (size_t)r * DDIM; dst = e2b + (size_t)r * DP + d0; }
    float v[8];
    if (d0 + 8 <= DDIM) {
        float4 lo = *(const float4*)(src + d0);
        float4 hi = *(const float4*)(src + d0 + 4);
        v[0] = lo.x; v[1] = lo.y; v[2] = lo.z; v[3] = lo.w;
        v[4] = hi.x; v[5] = hi.y; v[6] = hi.z; v[7] = hi.w;
    } else if (d0 < DDIM) {             // d0 == 296
        float4 lo = *(const float4*)(src + d0);
        v[0] = lo.x; v[1] = lo.y; v[2] = lo.z; v[3] = lo.w;
        v[4] = v[5] = v[6] = v[7] = 0.f;
    } else {
        for (int j = 0; j < 8; ++j) v[j] = 0.f;
    }
    unsigned short tmp[8];
#pragma unroll
    for (int j = 0; j < 8; ++j) tmp[j] = f2bf(v[j]);
    *(short8*)dst = *(short8*)tmp;
}

// ---------- prep: Wb (k,d,e) fp32 -> tiled+swizzled bf16 wbt_sw[k][et][e'][g'] ----------
// LDS-linear layout per (k,et): 32 rows (e') x 40 granules(16B); granule column
// g' = (g & ~7) | ((g ^ e') & 7)  -- XOR swizzle so MFMA A-frag reads are bank-balanced
// while the DMA writes LDS in pure linear order.
__global__ void prep_wbt(const float* __restrict__ Wb, unsigned short* __restrict__ wbt) {
    int k = blockIdx.x, dt = blockIdx.y, et = blockIdx.z;
    int tx = threadIdx.x & 31, ty = threadIdx.x >> 5;   // ty 0..7
    __shared__ float tile[32][33];
#pragma unroll
    for (int rr = 0; rr < 4; ++rr) {
        int d = dt * 32 + ty + rr * 8;
        int e = et * 32 + tx;
        tile[ty + rr * 8][tx] = (d < DDIM && e < DDIM) ? Wb[((size_t)k * DDIM + d) * DDIM + e] : 0.f;
    }
    __syncthreads();
#pragma unroll
    for (int rr = 0; rr < 4; ++rr) {
        int e_loc = ty + rr * 8;            // e' within tile
        int d = dt * 32 + tx;
        int g = d >> 3;
        int gp = (g & ~7) | ((g ^ e_loc) & 7);
        wbt[((size_t)(k * 10 + et) * 32 + e_loc) * DP + gp * 8 + (d & 7)] = f2bf(tile[tx][e_loc]);
    }
}

// ---------- prep: gate/tanh projections (coalesced over k, float4 e-loads) ----------
__global__ void prep_p_v3(const float* __restrict__ e1, const float* __restrict__ e2,
                          const float* __restrict__ Wd, const float* __restrict__ Wg,
                          float* __restrict__ p1d, float* __restrict__ p1g,
                          float* __restrict__ p2d, float* __restrict__ p2g) {
    const int bid = blockIdx.x;                 // 0..511, 16 rows each
    const int kk = threadIdx.x & 63;
    const int grp = threadIdx.x >> 6;           // 0..3 -> 4 rows each
    const int kks = kk < KDIM ? kk : 0;
    const float* src; int woff; float *dd, *dg; int r0;
    int rowbase = bid * 16;
    if (rowbase < 4096) { r0 = rowbase; src = e1; woff = 0; dd = p1d; dg = p1g; }
    else { r0 = rowbase - 4096; src = e2; woff = DDIM; dd = p2d; dg = p2g; }
    const float* e0 = src + (size_t)(r0 + grp * 4) * DDIM;
    const float* wdp = Wd + (size_t)woff * KDIM + kks;
    const float* wgp = Wg + (size_t)woff * KDIM + kks;

    float ad[4] = {0.f, 0.f, 0.f, 0.f}, ag[4] = {0.f, 0.f, 0.f, 0.f};
    for (int c = 0; c < DDIM / 4; ++c) {
        const int d0 = c * 4;
        float4 x[4];
#pragma unroll
        for (int rr = 0; rr < 4; ++rr)
            x[rr] = *(const float4*)(e0 + (size_t)rr * DDIM + d0);
        float wd0 = wdp[(size_t)(d0 + 0) * KDIM];
        float wd1 = wdp[(size_t)(d0 + 1) * KDIM];
        float wd2 = wdp[(size_t)(d0 + 2) * KDIM];
        float wd3 = wdp[(size_t)(d0 + 3) * KDIM];
        float wg0 = wgp[(size_t)(d0 + 0) * KDIM];
        float wg1 = wgp[(size_t)(d0 + 1) * KDIM];
        float wg2 = wgp[(size_t)(d0 + 2) * KDIM];
        float wg3 = wgp[(size_t)(d0 + 3) * KDIM];
#pragma unroll
        for (int rr = 0; rr < 4; ++rr) {
            ad[rr] += x[rr].x * wd0 + x[rr].y * wd1 + x[rr].z * wd2 + x[rr].w * wd3;
            ag[rr] += x[rr].x * wg0 + x[rr].y * wg1 + x[rr].z * wg2 + x[rr].w * wg3;
        }
    }
    if (kk < KDIM) {
#pragma unroll
        for (int rr = 0; rr < 4; ++rr) {
            size_t o = (size_t)(r0 + grp * 4 + rr) * KDIM + kk;
            dd[o] = ad[rr];
            dg[o] = ag[rr];
        }
    }
}

// ---------- main: per (b,k): S = (e1 Wb[k]) e2^T, gate, atomic-accumulate ----------
// 512 threads / 8 waves, wave owns 16 i-rows -> ~110 regs/wave -> 16 waves/CU.
// Staging via global_load_lds (no staging VGPRs); phase1 computes T^T fragments
// (A=wtile, B=e1) so T-writes are 2x ds_write_b64 instead of 16x ds_write_b16.
__global__ __launch_bounds__(512, 4) void grn_main(
    const unsigned short* __restrict__ e1b, const unsigned short* __restrict__ e2b,
    const unsigned short* __restrict__ wbt,
    const float* __restrict__ p1d, const float* __restrict__ p1g,
    const float* __restrict__ p2d, const float* __restrict__ p2g,
    const float* __restrict__ bg, const float* __restrict__ bb,
    const float* __restrict__ u, float* __restrict__ out) {
    const int b = blockIdx.x, k = blockIdx.y;
    const int tid = threadIdx.x;
    const int wid = tid >> 6, lane = tid & 63;
    const int q = lane >> 4, ln = lane & 15;
    const int rw0 = wid * 16;                      // wave owns i-rows [rw0, rw0+16)

    __shared__ __align__(16) unsigned short wtile[32 * DP];   // 20480B, swizzled rows e'
    __shared__ __align__(16) unsigned short e2t[LL * 32];     // 8192B, pitch 64B
    __shared__ __align__(16) unsigned short Tt[LL * TP];      // 10240B
    __shared__ float pbuf[4][LL];

    if (tid < LL) {
        int gi = (b * LL + tid) * KDIM + k;
        pbuf[0][tid] = p1d[gi];
        pbuf[1][tid] = p1g[gi];
        pbuf[2][tid] = p2d[gi];
        pbuf[3][tid] = p2g[gi];
    }
    const float u_k = u[k], bg_k = bg[k], b_k = bb[k];

    // e1 B-fragments: lane holds e1[i=rw0+ln][d=kd*32+q*8+j], reused all e-tiles
    short8 af[10];
    {
        const unsigned short* p = e1b + ((size_t)(b * LL + rw0 + ln)) * DP + q * 8;
#pragma unroll
        for (int kd = 0; kd < 10; ++kd) af[kd] = *(const short8*)(p + kd * 32);
    }

    // DMA source addresses
    const unsigned short* wsrc = wbt + (size_t)k * (10 * 32 * DP);
    const int wg0 = wid * 512 + lane * 8;          // elems; granule = chunk*64+lane
    const int wg1 = (wid + 8) * 512 + lane * 8;
    const int wg2 = (wid + 16) * 512 + lane * 8;
    const unsigned short* esrc = e2b + ((size_t)(b * LL + ((wid * 64 + lane) >> 2))) * DP + (lane & 3) * 8;

    // swizzled wtile read bases (bytes): row ln (and +16 via imm), s = ln&7
    const int s = ln & 7;
    const int we_base = ln * 640 + ((q ^ s) << 4);          // kd even
    const int wo_base = ln * 640 + ((((4 + q)) ^ s) << 4);  // kd odd

    float4v S[8];
#pragma unroll
    for (int nt = 0; nt < 8; ++nt) S[nt] = (float4v){0.f, 0.f, 0.f, 0.f};

#pragma unroll 1
    for (int et = 0; et < 10; ++et) {
        // stage tile via DMA: wtile 20 chunks of 1KB, e2t 8 chunks
        const unsigned short* wt = wsrc + et * 10240;
        dma16(wt + wg0, (char*)wtile + wid * 1024);
        dma16(wt + wg1, (char*)wtile + (wid + 8) * 1024);
        if (wid < 4) dma16(wt + wg2, (char*)wtile + (wid + 16) * 1024);
        dma16(esrc + et * 32, (char*)e2t + wid * 1024);
        __syncthreads();   // vmcnt(0) drain -> DMA complete

        // phase 1: T^T frags: mfma(A=wtile[e'], B=e1[i]) -> C[m=e'][n=i]
        float4v t0 = (float4v){0.f, 0.f, 0.f, 0.f};
        float4v t1 = (float4v){0.f, 0.f, 0.f, 0.f};
#pragma unroll
        for (int kd = 0; kd < 10; ++kd) {
            const int off = (kd >> 1) * 128;
            const int base = (kd & 1) ? wo_base : we_base;
            short8 wa0 = *(const short8*)((const char*)wtile + base + off);
            short8 wa1 = *(const short8*)((const char*)wtile + base + off + 10240);
            t0 = mfma16(wa0, af[kd], t0);
            t1 = mfma16(wa1, af[kd], t1);
        }
        // T write: lane (q,ln) holds rows e'=mte*16+q*4+0..3, col i=rw0+ln
        // -> Tt[i][e'] : 4 consecutive e' => one b64 per m-tile (wave-private rows)
        {
            char* tw = (char*)Tt + (rw0 + ln) * 80 + q * 8;
            uint2 v0; v0.x = pack2bf(t0[0], t0[1]); v0.y = pack2bf(t0[2], t0[3]);
            *(uint2*)tw = v0;
            uint2 v1; v1.x = pack2bf(t1[0], t1[1]); v1.y = pack2bf(t1[2], t1[3]);
            *(uint2*)(tw + 32) = v1;
        }
        // phase 2: S[i][j] += sum_e' T[i][e'] * e2t[j][e']
        short8 a0 = *(const short8*)((const char*)Tt + (rw0 + ln) * 80 + q * 16);
#pragma unroll
        for (int nt = 0; nt < 8; ++nt) {
            short8 bf = *(const short8*)((const char*)e2t + (nt * 16 + ln) * 64 + q * 16);
            S[nt] = mfma16(a0, bf, S[nt]);
        }
        __syncthreads();   // all reads done before next tile's DMA overwrites
    }

    // epilogue: gate, mix, scale by u[k], atomic accumulate over k
    float pdi[4], pgi[4];
#pragma unroll
    for (int r = 0; r < 4; ++r) {
        int i = rw0 + q * 4 + r;
        pdi[r] = pbuf[0][i];
        pgi[r] = pbuf[1][i];
    }
    size_t obase = (size_t)b * LL * LL;
#pragma unroll
    for (int nt = 0; nt < 8; ++nt) {
        int j = nt * 16 + ln;
        float pdj = pbuf[2][j];
        float pgj = pbuf[3][j] + bg_k;
#pragma unroll
        for (int r = 0; r < 4; ++r) {
            int i = rw0 + q * 4 + r;
            float btp = S[nt][r];
            float sd = pdi[r] + pdj;
            float sg = pgi[r] + pgj;
            float e2x = __expf(2.f * sd);
            float sln = 1.f - 2.f * __builtin_amdgcn_rcpf(e2x + 1.f);   // tanh(sd)
            float g = __builtin_amdgcn_rcpf(1.f + __expf(-sg));          // sigmoid(sg)
            float val = u_k * (g * btp + (1.f - g) * sln + b_k);
            unsafeAtomicAdd(out + obase + (size_t)i * LL + j, val);
        }
    }
}

extern "C" void kernel_launch(void* const* d_in, const int* in_sizes, int n_in,
                              void* d_out, int out_size, void* d_ws, size_t ws_size,
                              hipStream_t stream) {
    const float* e1 = (const float*)d_in[0];   // (32,128,300)
    const float* e2 = (const float*)d_in[1];   // (32,128,300)
    const float* Wb = (const float*)d_in[2];   // (50,300,300)
    const float* Wd = (const float*)d_in[3];   // (600,50)
    const float* Wg = (const float*)d_in[4];   // (600,50)
    const float* bg = (const float*)d_in[5];   // (50,)
    const float* bb = (const float*)d_in[6];   // (50,)
    const float* u  = (const float*)d_in[7];   // (50,1)
    float* out = (float*)d_out;                // (32,128,128,1)

    // workspace layout (16B-aligned blocks)
    unsigned short* e1b = (unsigned short*)d_ws;                 // 1,310,720 elems
    unsigned short* e2b = e1b + 1310720;                         // 1,310,720 elems
    unsigned short* wbt = e2b + 1310720;                         // 5,120,000 elems (tiled+swizzled)
    float* pf  = (float*)((char*)d_ws + 15482880);
    float* p1d = pf;
    float* p1g = pf + 204800;
    float* p2d = pf + 409600;
    float* p2g = pf + 614400;                                    // end 18,759,680 B

    hipMemsetAsync(d_out, 0, (size_t)out_size * sizeof(float), stream);

    prep_convert<<<1280, 256, 0, stream>>>(e1, e2, e1b, e2b);
    prep_wbt<<<dim3(KDIM, 10, 10), 256, 0, stream>>>(Wb, wbt);
    prep_p_v3<<<512, 256, 0, stream>>>(e1, e2, Wd, Wg, p1d, p1g, p2d, p2g);
    grn_main<<<dim3(NB, KDIM), 512, 0, stream>>>(e1b, e2b, wbt,
                                                 p1d, p1g, p2d, p2g,
                                                 bg, bb, u, out);
}

// Round 6
// 236.881 us; speedup vs baseline: 1.1411x; 1.1411x over previous
//
#include <hip/hip_runtime.h>
#include <hip/hip_bf16.h>

typedef __attribute__((ext_vector_type(8))) short short8;
typedef __attribute__((ext_vector_type(4))) float float4v;

#define NB 32
#define LL 128
#define DDIM 300
#define DP 320
#define KDIM 50
#define WP 328   // wtile pitch (bf16 elems)
#define TP 40    // T/e2t pitch
#define SLAB_OFF 18759680ull
#define WS_NEED  (18759680ull + 104857600ull)

__device__ __forceinline__ unsigned short f2bf(float x) {
    unsigned int u = __float_as_uint(x);
    unsigned int r = (u + 0x7FFFu + ((u >> 16) & 1u)) >> 16;
    return (unsigned short)r;
}

__device__ __forceinline__ float4v mfma16(short8 a, short8 b, float4v c) {
    return __builtin_amdgcn_mfma_f32_16x16x32_bf16(a, b, c, 0, 0, 0);
}

// ---------- prep: e1/e2 -> bf16, D padded 300->320 with zeros (float4 loads) ----------
__global__ void prep_convert(const float* __restrict__ e1, const float* __restrict__ e2,
                             unsigned short* __restrict__ e1b, unsigned short* __restrict__ e2b) {
    int gid = blockIdx.x * 256 + threadIdx.x;     // 8192 rows * 40 granules
    int row = gid / 40;
    int d0 = (gid % 40) * 8;
    const float* src;
    unsigned short* dst;
    if (row < 4096) { src = e1 + (size_t)row * DDIM; dst = e1b + (size_t)row * DP + d0; }
    else { int r = row - 4096; src = e2 + (size_t)r * DDIM; dst = e2b + (size_t)r * DP + d0; }
    float v[8];
    if (d0 + 8 <= DDIM) {
        float4 lo = *(const float4*)(src + d0);
        float4 hi = *(const float4*)(src + d0 + 4);
        v[0] = lo.x; v[1] = lo.y; v[2] = lo.z; v[3] = lo.w;
        v[4] = hi.x; v[5] = hi.y; v[6] = hi.z; v[7] = hi.w;
    } else if (d0 < DDIM) {             // d0 == 296
        float4 lo = *(const float4*)(src + d0);
        v[0] = lo.x; v[1] = lo.y; v[2] = lo.z; v[3] = lo.w;
        v[4] = v[5] = v[6] = v[7] = 0.f;
    } else {
        for (int j = 0; j < 8; ++j) v[j] = 0.f;
    }
    unsigned short tmp[8];
#pragma unroll
    for (int j = 0; j < 8; ++j) tmp[j] = f2bf(v[j]);
    *(short8*)dst = *(short8*)tmp;
}

// ---------- prep: Wb (k,d,e) fp32 -> Wbt (k,e,d) bf16, padded to 320x320 ----------
// grid (KDIM, 10 e-tiles); dt-loop inside (500 blocks instead of 5000)
__global__ void prep_wbt(const float* __restrict__ Wb, unsigned short* __restrict__ wbt) {
    int k = blockIdx.x, et = blockIdx.y;
    int tx = threadIdx.x & 31, ty = threadIdx.x >> 5;   // ty 0..7
    __shared__ float tile[32][33];
    for (int dt = 0; dt < 10; ++dt) {
#pragma unroll
        for (int rr = 0; rr < 4; ++rr) {
            int d = dt * 32 + ty + rr * 8;
            int e = et * 32 + tx;
            tile[ty + rr * 8][tx] = (d < DDIM && e < DDIM) ? Wb[((size_t)k * DDIM + d) * DDIM + e] : 0.f;
        }
        __syncthreads();
#pragma unroll
        for (int rr = 0; rr < 4; ++rr) {
            int e = et * 32 + ty + rr * 8;
            int d = dt * 32 + tx;
            wbt[((size_t)k * DP + e) * DP + d] = f2bf(tile[tx][ty + rr * 8]);
        }
        __syncthreads();
    }
}

// ---------- prep: gate/tanh projections (coalesced over k, float4 e-loads) ----------
__global__ void prep_p_v3(const float* __restrict__ e1, const float* __restrict__ e2,
                          const float* __restrict__ Wd, const float* __restrict__ Wg,
                          float* __restrict__ p1d, float* __restrict__ p1g,
                          float* __restrict__ p2d, float* __restrict__ p2g) {
    const int bid = blockIdx.x;                 // 0..511, 16 rows each
    const int kk = threadIdx.x & 63;
    const int grp = threadIdx.x >> 6;           // 0..3 -> 4 rows each
    const int kks = kk < KDIM ? kk : 0;
    const float* src; int woff; float *dd, *dg; int r0;
    int rowbase = bid * 16;
    if (rowbase < 4096) { r0 = rowbase; src = e1; woff = 0; dd = p1d; dg = p1g; }
    else { r0 = rowbase - 4096; src = e2; woff = DDIM; dd = p2d; dg = p2g; }
    const float* e0 = src + (size_t)(r0 + grp * 4) * DDIM;
    const float* wdp = Wd + (size_t)woff * KDIM + kks;
    const float* wgp = Wg + (size_t)woff * KDIM + kks;

    float ad[4] = {0.f, 0.f, 0.f, 0.f}, ag[4] = {0.f, 0.f, 0.f, 0.f};
    for (int c = 0; c < DDIM / 4; ++c) {
        const int d0 = c * 4;
        float4 x[4];
#pragma unroll
        for (int rr = 0; rr < 4; ++rr)
            x[rr] = *(const float4*)(e0 + (size_t)rr * DDIM + d0);
        float wd0 = wdp[(size_t)(d0 + 0) * KDIM];
        float wd1 = wdp[(size_t)(d0 + 1) * KDIM];
        float wd2 = wdp[(size_t)(d0 + 2) * KDIM];
        float wd3 = wdp[(size_t)(d0 + 3) * KDIM];
        float wg0 = wgp[(size_t)(d0 + 0) * KDIM];
        float wg1 = wgp[(size_t)(d0 + 1) * KDIM];
        float wg2 = wgp[(size_t)(d0 + 2) * KDIM];
        float wg3 = wgp[(size_t)(d0 + 3) * KDIM];
#pragma unroll
        for (int rr = 0; rr < 4; ++rr) {
            ad[rr] += x[rr].x * wd0 + x[rr].y * wd1 + x[rr].z * wd2 + x[rr].w * wd3;
            ag[rr] += x[rr].x * wg0 + x[rr].y * wg1 + x[rr].z * wg2 + x[rr].w * wg3;
        }
    }
    if (kk < KDIM) {
#pragma unroll
        for (int rr = 0; rr < 4; ++rr) {
            size_t o = (size_t)(r0 + grp * 4 + rr) * KDIM + kk;
            dd[o] = ad[rr];
            dg[o] = ag[rr];
        }
    }
}

// ---------- main: per (b,k): S = (e1 Wb[k]) e2^T, gate;
// SLAB=1: plain stores to slab[k][b][i][j] (no atomics). SLAB=0: atomicAdd to out. ----------
template <int SLAB>
__global__ __launch_bounds__(256, 2) void grn_main(
    const unsigned short* __restrict__ e1b, const unsigned short* __restrict__ e2b,
    const unsigned short* __restrict__ wbt,
    const float* __restrict__ p1d, const float* __restrict__ p1g,
    const float* __restrict__ p2d, const float* __restrict__ p2g,
    const float* __restrict__ bg, const float* __restrict__ bb,
    const float* __restrict__ u, float* __restrict__ out) {
    const int b = blockIdx.x, k = blockIdx.y;
    const int tid = threadIdx.x;
    const int wid = tid >> 6, lane = tid & 63;
    const int q = lane >> 4, ln = lane & 15;
    const int rw0 = wid * 32;                      // wave owns S/T rows [rw0, rw0+32)

    __shared__ __align__(16) unsigned short wtile[32 * WP];   // Wbt tile [e'][d]
    __shared__ __align__(16) unsigned short Tt[128 * TP];     // T tile   [i][e']
    __shared__ __align__(16) unsigned short e2t[128 * TP];    // e2 tile  [j][e']
    __shared__ float pbuf[4][128];

    if (tid < 128) {
        int gi = (b * LL + tid) * KDIM + k;
        pbuf[0][tid] = p1d[gi];
        pbuf[1][tid] = p1g[gi];
        pbuf[2][tid] = p2d[gi];
        pbuf[3][tid] = p2g[gi];
    }
    const float u_k = u[k], bg_k = bg[k], b_k = bb[k];

    const unsigned short* wbt_k = wbt + (size_t)k * DP * DP;
    size_t wgo[5]; int wlo[5];
#pragma unroll
    for (int it = 0; it < 5; ++it) {
        int c = tid + it * 256, r = c / 40, col = (c % 40) * 8;
        wgo[it] = (size_t)r * DP + col;
        wlo[it] = r * WP + col;
    }
    size_t ego[2]; int elo[2];
#pragma unroll
    for (int it = 0; it < 2; ++it) {
        int c = tid + it * 256, j = c >> 2, col = (c & 3) * 8;
        ego[it] = (size_t)(b * LL + j) * DP + col;
        elo[it] = j * TP + col;
    }

    // e1 A-fragments, loaded once, reused across all e-tiles.
    short8 af[2][10];
#pragma unroll
    for (int mt = 0; mt < 2; ++mt) {
        int row = rw0 + mt * 16 + ln;
        const unsigned short* p = e1b + ((size_t)(b * LL + row)) * DP + q * 8;
#pragma unroll
        for (int kd = 0; kd < 10; ++kd)
            af[mt][kd] = *(const short8*)(p + kd * 32);
    }

    float4v S[2][8];
#pragma unroll
    for (int mt = 0; mt < 2; ++mt)
#pragma unroll
        for (int nt = 0; nt < 8; ++nt)
            S[mt][nt] = (float4v){0.f, 0.f, 0.f, 0.f};

    // prefetch tile 0
    short8 wpre[5], epre[2];
#pragma unroll
    for (int it = 0; it < 5; ++it) wpre[it] = *(const short8*)(wbt_k + wgo[it]);
#pragma unroll
    for (int it = 0; it < 2; ++it) epre[it] = *(const short8*)(e2b + ego[it]);

    for (int et = 0; et < 10; ++et) {
#pragma unroll
        for (int it = 0; it < 5; ++it) *(short8*)&wtile[wlo[it]] = wpre[it];
#pragma unroll
        for (int it = 0; it < 2; ++it) *(short8*)&e2t[elo[it]] = epre[it];
        __syncthreads();

        if (et < 9) {
            const size_t ew = (size_t)(et + 1) * 32 * DP;
            const int ee = (et + 1) * 32;
#pragma unroll
            for (int it = 0; it < 5; ++it) wpre[it] = *(const short8*)(wbt_k + ew + wgo[it]);
#pragma unroll
            for (int it = 0; it < 2; ++it) epre[it] = *(const short8*)(e2b + ego[it] + ee);
        }

        // phase 1: T[i][e'] = sum_d e1[i][d] * Wbt[e'][d]
        float4v tacc[2][2];
#pragma unroll
        for (int mt = 0; mt < 2; ++mt)
#pragma unroll
            for (int nt = 0; nt < 2; ++nt)
                tacc[mt][nt] = (float4v){0.f, 0.f, 0.f, 0.f};
#pragma unroll
        for (int kd = 0; kd < 10; ++kd) {
            short8 bf0 = *(const short8*)&wtile[(ln) * WP + kd * 32 + q * 8];
            short8 bf1 = *(const short8*)&wtile[(16 + ln) * WP + kd * 32 + q * 8];
            tacc[0][0] = mfma16(af[0][kd], bf0, tacc[0][0]);
            tacc[0][1] = mfma16(af[0][kd], bf1, tacc[0][1]);
            tacc[1][0] = mfma16(af[1][kd], bf0, tacc[1][0]);
            tacc[1][1] = mfma16(af[1][kd], bf1, tacc[1][1]);
        }
#pragma unroll
        for (int mt = 0; mt < 2; ++mt)
#pragma unroll
            for (int nt = 0; nt < 2; ++nt)
#pragma unroll
                for (int r = 0; r < 4; ++r) {
                    int row = rw0 + mt * 16 + q * 4 + r;
                    Tt[row * TP + nt * 16 + ln] = f2bf(tacc[mt][nt][r]);
                }
        // phase 2: S[i][j] += sum_e' T[i][e'] * e2t[j][e']
        short8 a0 = *(const short8*)&Tt[(rw0 + ln) * TP + q * 8];
        short8 a1 = *(const short8*)&Tt[(rw0 + 16 + ln) * TP + q * 8];
#pragma unroll
        for (int nt = 0; nt < 8; ++nt) {
            short8 bf = *(const short8*)&e2t[(nt * 16 + ln) * TP + q * 8];
            S[0][nt] = mfma16(a0, bf, S[0][nt]);
            S[1][nt] = mfma16(a1, bf, S[1][nt]);
        }
        __syncthreads();
    }

    // epilogue: gate, mix, scale by u[k]; write (slab plain stores | atomics)
    float pdi[2][4], pgi[2][4];
#pragma unroll
    for (int mt = 0; mt < 2; ++mt)
#pragma unroll
        for (int r = 0; r < 4; ++r) {
            int i = rw0 + mt * 16 + q * 4 + r;
            pdi[mt][r] = pbuf[0][i];
            pgi[mt][r] = pbuf[1][i];
        }
    float* dst = SLAB ? (out + ((size_t)k * NB + b) * (LL * LL))
                      : (out + (size_t)b * LL * LL);
#pragma unroll
    for (int nt = 0; nt < 8; ++nt) {
        int j = nt * 16 + ln;
        float pdj = pbuf[2][j];
        float pgj = pbuf[3][j] + bg_k;
#pragma unroll
        for (int mt = 0; mt < 2; ++mt)
#pragma unroll
            for (int r = 0; r < 4; ++r) {
                int i = rw0 + mt * 16 + q * 4 + r;
                float btp = S[mt][nt][r];
                float sd = pdi[mt][r] + pdj;
                float sg = pgi[mt][r] + pgj;
                float e2x = __expf(2.f * sd);
                float sln = 1.f - 2.f * __builtin_amdgcn_rcpf(e2x + 1.f);   // tanh(sd)
                float g = __builtin_amdgcn_rcpf(1.f + __expf(-sg));          // sigmoid(sg)
                float val = u_k * (g * btp + (1.f - g) * sln + b_k);
                if (SLAB) dst[(size_t)i * LL + j] = val;
                else      unsafeAtomicAdd(dst + (size_t)i * LL + j, val);
            }
    }
}

// ---------- reduce: out[x] = sum_k slab[k][x], float4 ----------
__global__ void reduce_k(const float* __restrict__ slab, float* __restrict__ out) {
    int idx = blockIdx.x * 256 + threadIdx.x;     // 0..131071 float4s
    const float4* s4 = (const float4*)slab;
    float4 a0 = {0.f, 0.f, 0.f, 0.f}, a1 = {0.f, 0.f, 0.f, 0.f};
#pragma unroll
    for (int k = 0; k < KDIM; k += 2) {
        float4 x = s4[(size_t)k * 131072 + idx];
        float4 y = s4[(size_t)(k + 1) * 131072 + idx];
        a0.x += x.x; a0.y += x.y; a0.z += x.z; a0.w += x.w;
        a1.x += y.x; a1.y += y.y; a1.z += y.z; a1.w += y.w;
    }
    float4 r;
    r.x = a0.x + a1.x; r.y = a0.y + a1.y; r.z = a0.z + a1.z; r.w = a0.w + a1.w;
    ((float4*)out)[idx] = r;
}

extern "C" void kernel_launch(void* const* d_in, const int* in_sizes, int n_in,
                              void* d_out, int out_size, void* d_ws, size_t ws_size,
                              hipStream_t stream) {
    const float* e1 = (const float*)d_in[0];   // (32,128,300)
    const float* e2 = (const float*)d_in[1];   // (32,128,300)
    const float* Wb = (const float*)d_in[2];   // (50,300,300)
    const float* Wd = (const float*)d_in[3];   // (600,50)
    const float* Wg = (const float*)d_in[4];   // (600,50)
    const float* bg = (const float*)d_in[5];   // (50,)
    const float* bb = (const float*)d_in[6];   // (50,)
    const float* u  = (const float*)d_in[7];   // (50,1)
    float* out = (float*)d_out;                // (32,128,128,1)

    unsigned short* e1b = (unsigned short*)d_ws;                 // 1,310,720 elems
    unsigned short* e2b = e1b + 1310720;                         // 1,310,720 elems
    unsigned short* wbt = e2b + 1310720;                         // 5,120,000 elems
    float* pf  = (float*)((char*)d_ws + 15482880);
    float* p1d = pf;
    float* p1g = pf + 204800;
    float* p2d = pf + 409600;
    float* p2g = pf + 614400;                                    // end 18,759,680 B
    float* slab = (float*)((char*)d_ws + SLAB_OFF);              // 50 x 524288 floats

    prep_convert<<<1280, 256, 0, stream>>>(e1, e2, e1b, e2b);
    prep_wbt<<<dim3(KDIM, 10), 256, 0, stream>>>(Wb, wbt);
    prep_p_v3<<<512, 256, 0, stream>>>(e1, e2, Wd, Wg, p1d, p1g, p2d, p2g);

    if (ws_size >= WS_NEED) {
        grn_main<1><<<dim3(NB, KDIM), 256, 0, stream>>>(e1b, e2b, wbt,
                                                        p1d, p1g, p2d, p2g,
                                                        bg, bb, u, slab);
        reduce_k<<<512, 256, 0, stream>>>(slab, out);
    } else {
        hipMemsetAsync(d_out, 0, (size_t)out_size * sizeof(float), stream);
        grn_main<0><<<dim3(NB, KDIM), 256, 0, stream>>>(e1b, e2b, wbt,
                                                        p1d, p1g, p2d, p2g,
                                                        bg, bb, u, out);
    }
}